// Round 11
// baseline (95.633 us; speedup 1.0000x reference)
//
#include <hip/hip_runtime.h>

typedef short short4v __attribute__((ext_vector_type(4)));
typedef short short8 __attribute__((ext_vector_type(8)));
typedef float floatx4 __attribute__((ext_vector_type(4)));

// Native bf16 conversion: compiler emits packed v_cvt_pk_bf16_f32 (RTNE).
__device__ __forceinline__ short f2bf(float f) {
    __bf16 h = (__bf16)f;
    return __builtin_bit_cast(short, h);
}
__device__ __forceinline__ float bf2f(short s) {
    unsigned u = ((unsigned)(unsigned short)s) << 16;
    return __builtin_bit_cast(float, u);
}

// Convert lora_A (4096x64) and lora_B (64x4096) fp32 -> bf16 in MFMA fragment
// layout for mfma_f32_16x16x32_bf16:
//   lane l holds elem[k][c] with c = l&15, k = 8*(l>>4) + j, j=0..7
__global__ __launch_bounds__(256) void conv_ab(
    const float* __restrict__ A, const float* __restrict__ B,
    short* __restrict__ Abf, short* __restrict__ Bbf) {
    int i = blockIdx.x * 256 + threadIdx.x;   // 0 .. 262143
    int j    = i & 7;
    int lane = (i >> 3) & 63;
    int hi   = i >> 9;                        // A: ks*4+nt ; B: ct*2+ks
    int krow = 8 * (lane >> 4) + j;
    int cc   = lane & 15;
    {   // A fragments
        int ks = hi >> 2, nt = hi & 3;
        Abf[i] = f2bf(A[(size_t)(ks * 32 + krow) * 64 + nt * 16 + cc]);
    }
    {   // B fragments
        int ct = hi >> 1, ks = hi & 1;
        Bbf[i] = f2bf(B[(size_t)(ks * 32 + krow) * 4096 + ct * 16 + cc]);
    }
}

// k1: 8 bf16 split-K partials of t = x @ A.  Grid (1024, 2) x 4 waves.
// SLIM build: <=64 VGPR so 8 waves/SIMD (32/CU) — TLP, not ILP, hides the
// L3-distance x latency. Only the x stream is 1-ahead prefetched; A-frags
// (L2-resident) are demand-loaded. Operand-SWAPPED mfma -> lane holds 4
// consecutive t-cols of ONE row -> direct 8B stores. No LDS, no barriers.
__global__ __launch_bounds__(256, 8) void k1_xA(
    const float* __restrict__ x, const float* __restrict__ tw,
    const short* __restrict__ Abf, short* __restrict__ t8) {
    const int lane = threadIdx.x & 63;
    const int wave = threadIdx.x >> 6;
    const int rowbase = blockIdx.x * 16;
    const int rrow = lane & 15;
    const int kgrp = lane >> 4;
    const int p = blockIdx.y * 4 + wave;      // ksplit 0..7
    const int kbase = p * 512;

    const int row = rowbase + rrow;
    const bool active = (tw[row] != 0.0f);
    const floatx4* xv = (const floatx4*)(x + (size_t)row * 4096 + kbase + kgrp * 8);
    // Abf8[(ksg*4+nt)*64 + lane], ksg = kbase/32 + ks
    const short8* ap = (const short8*)Abf + ((size_t)(kbase >> 5) * 256) + lane;

    floatx4 acc0 = {0,0,0,0}, acc1 = {0,0,0,0}, acc2 = {0,0,0,0}, acc3 = {0,0,0,0};

    // 1-ahead prefetch of the x stream only
    floatx4 cx0 = {0,0,0,0}, cx1 = {0,0,0,0};
    if (active) { cx0 = xv[0]; cx1 = xv[1]; }

    #pragma unroll 4
    for (int ks = 0; ks < 16; ++ks) {
        const int kn = (ks + 1 < 16) ? ks + 1 : 15;
        floatx4 nx0 = {0,0,0,0}, nx1 = {0,0,0,0};
        if (active) { nx0 = xv[kn * 8]; nx1 = xv[kn * 8 + 1]; }

        short8 b0 = ap[ks * 256 + 0 * 64];
        short8 b1 = ap[ks * 256 + 1 * 64];
        short8 b2 = ap[ks * 256 + 2 * 64];
        short8 b3 = ap[ks * 256 + 3 * 64];

        short8 xa;
        xa[0] = f2bf(cx0[0]); xa[1] = f2bf(cx0[1]);
        xa[2] = f2bf(cx0[2]); xa[3] = f2bf(cx0[3]);
        xa[4] = f2bf(cx1[0]); xa[5] = f2bf(cx1[1]);
        xa[6] = f2bf(cx1[2]); xa[7] = f2bf(cx1[3]);

        // swapped: A-matrix fragment as A-operand, x fragment as B-operand.
        // D[m][n] = sum_k A[kbase+k][nt*16+m] * x[rowbase+n][kbase+k]
        acc0 = __builtin_amdgcn_mfma_f32_16x16x32_bf16(b0, xa, acc0, 0, 0, 0);
        acc1 = __builtin_amdgcn_mfma_f32_16x16x32_bf16(b1, xa, acc1, 0, 0, 0);
        acc2 = __builtin_amdgcn_mfma_f32_16x16x32_bf16(b2, xa, acc2, 0, 0, 0);
        acc3 = __builtin_amdgcn_mfma_f32_16x16x32_bf16(b3, xa, acc3, 0, 0, 0);

        cx0 = nx0; cx1 = nx1;
    }

    // D layout: n = lane&15 (token row), m = 4*kgrp + b (t-col within n-tile)
    // -> lane holds t_p[row][nt*16 + kgrp*4 + 0..3]: contiguous 8B per nt.
    short* tp = t8 + (size_t)p * (16384 * 64) + (size_t)row * 64 + kgrp * 4;
    floatx4 accs[4] = {acc0, acc1, acc2, acc3};
    #pragma unroll
    for (int nt = 0; nt < 4; ++nt) {
        short4v v;
        v[0] = f2bf(accs[nt][0]); v[1] = f2bf(accs[nt][1]);
        v[2] = f2bf(accs[nt][2]); v[3] = f2bf(accs[nt][3]);
        *(short4v*)(tp + nt * 16) = v;
    }
}

// k1.5: t = sum of 8 bf16 partials (f32 accumulate). 1M elems / 4 per thread.
__global__ __launch_bounds__(256) void k1_sum(
    const short* __restrict__ t8, short* __restrict__ t) {
    const int i = blockIdx.x * 256 + threadIdx.x;   // 0 .. 262143
    const size_t off = (size_t)i * 4;
    float s0 = 0.f, s1 = 0.f, s2 = 0.f, s3 = 0.f;
    #pragma unroll
    for (int p = 0; p < 8; ++p) {
        short4v v = *(const short4v*)(t8 + (size_t)p * (16384 * 64) + off);
        s0 += bf2f(v[0]); s1 += bf2f(v[1]); s2 += bf2f(v[2]); s3 += bf2f(v[3]);
    }
    short4v r;
    r[0] = f2bf(s0); r[1] = f2bf(s1); r[2] = f2bf(s2); r[3] = f2bf(s3);
    *(short4v*)(t + off) = r;
}

// k2: out = (t @ B) * tw * 2, operand-swapped MFMA, LDS-staged epilogue.
// 16384 blocks x 4 waves: block = 16 rows x 256 cols; wave w computes cols
// [64w,64w+64), stages f32 tile in LDS, then row-linear NT float4 stores
// (lanes 0-15 cover 256B contiguous per row).
__global__ __launch_bounds__(256, 4) void k2_tB(
    const short* __restrict__ t, const float* __restrict__ tw,
    const short* __restrict__ Bbf, float* __restrict__ out) {
    __shared__ float tile[16][257];       // +1 float pad (16.4 KB)

    const int lane = threadIdx.x & 63;
    const int wave = threadIdx.x >> 6;
    const int rg = blockIdx.x >> 4;
    const int cs = blockIdx.x & 15;
    const int rowbase = rg * 16;
    const int colblk = cs * 256;
    const int rrow = lane & 15;
    const int kgrp = lane >> 4;
    const int kofs = kgrp * 8;

    // t fragment (MFMA B-operand): lane holds t[rowbase+rrow][kofs+j]
    const short* t0 = t + (size_t)(rowbase + rrow) * 64 + kofs;
    short8 a0 = *(const short8*)t0;
    short8 a1 = *(const short8*)(t0 + 32);

    // B fragments (MFMA A-operand): Bbf8[(ct*2+ks)*64 + lane], ct = col/16
    const short8* bp = (const short8*)Bbf + (size_t)((colblk + wave * 64) >> 4) * 128 + lane;

    const float w = tw[rowbase + rrow] * 2.0f;

    #pragma unroll
    for (int nt = 0; nt < 4; ++nt) {
        short8 b0 = bp[(nt * 2 + 0) * 64];
        short8 b1 = bp[(nt * 2 + 1) * 64];
        floatx4 acc = {0, 0, 0, 0};
        // swapped: lane holds out[rrow][wave*64 + nt*16 + kgrp*4 + 0..3]
        acc = __builtin_amdgcn_mfma_f32_16x16x32_bf16(b0, a0, acc, 0, 0, 0);
        acc = __builtin_amdgcn_mfma_f32_16x16x32_bf16(b1, a1, acc, 0, 0, 0);
        acc[0] *= w; acc[1] *= w; acc[2] *= w; acc[3] *= w;
        *(floatx4*)&tile[rrow][wave * 64 + nt * 16 + kgrp * 4] = acc;
    }
    __syncthreads();

    // row-linear write-out: wave w -> rows 4w..4w+3; lane l -> row 4w+(l>>4),
    // 16B chunk (l&15)*16B within each 64-float column group q.
    const int orow_i = 4 * wave + (lane >> 4);
    float* orow = out + (size_t)(rowbase + orow_i) * 4096 + colblk;
    #pragma unroll
    for (int q = 0; q < 4; ++q) {
        const int c = q * 64 + rrow * 4;
        floatx4 v = *(const floatx4*)&tile[orow_i][c];
        __builtin_nontemporal_store(v, (floatx4*)(orow + c));
    }
}

extern "C" void kernel_launch(void* const* d_in, const int* in_sizes, int n_in,
                              void* d_out, int out_size, void* d_ws, size_t ws_size,
                              hipStream_t stream) {
    const float* x  = (const float*)d_in[0];   // (8,2048,4096)
    const float* tw = (const float*)d_in[1];   // (8,2048)
    const float* A  = (const float*)d_in[2];   // (4096,64)
    const float* B  = (const float*)d_in[3];   // (64,4096)
    float* out = (float*)d_out;                // (8,2048,4096) fp32

    short* Abf = (short*)d_ws;                 // 512 KB
    short* Bbf = Abf + 262144;                 // 512 KB
    short* t8  = Bbf + 262144;                 // 8 x 16384 x 64 bf16 = 16 MB
    short* t   = t8 + (size_t)8 * 16384 * 64;  // 2 MB

    conv_ab<<<1024, 256, 0, stream>>>(A, B, Abf, Bbf);
    k1_xA<<<dim3(1024, 2), 256, 0, stream>>>(x, tw, Abf, t8);
    k1_sum<<<1024, 256, 0, stream>>>(t8, t);
    k2_tB<<<16384, 256, 0, stream>>>(t, tw, Bbf, out);
}

// Round 12
// 95.344 us; speedup vs baseline: 1.0030x; 1.0030x over previous
//
#include <hip/hip_runtime.h>

typedef short short4v __attribute__((ext_vector_type(4)));
typedef short short8 __attribute__((ext_vector_type(8)));
typedef float floatx4 __attribute__((ext_vector_type(4)));

// Native bf16 conversion: compiler emits packed v_cvt_pk_bf16_f32 (RTNE).
__device__ __forceinline__ short f2bf(float f) {
    __bf16 h = (__bf16)f;
    return __builtin_bit_cast(short, h);
}
__device__ __forceinline__ float bf2f(short s) {
    unsigned u = ((unsigned)(unsigned short)s) << 16;
    return __builtin_bit_cast(float, u);
}

// Convert lora_A (4096x64) and lora_B (64x4096) fp32 -> bf16 in MFMA fragment
// layout for mfma_f32_16x16x32_bf16:
//   lane l holds elem[k][c] with c = l&15, k = 8*(l>>4) + j, j=0..7
__global__ __launch_bounds__(256) void conv_ab(
    const float* __restrict__ A, const float* __restrict__ B,
    short* __restrict__ Abf, short* __restrict__ Bbf) {
    int i = blockIdx.x * 256 + threadIdx.x;   // 0 .. 262143
    int j    = i & 7;
    int lane = (i >> 3) & 63;
    int hi   = i >> 9;                        // A: ks*4+nt ; B: ct*2+ks
    int krow = 8 * (lane >> 4) + j;
    int cc   = lane & 15;
    {   // A fragments
        int ks = hi >> 2, nt = hi & 3;
        Abf[i] = f2bf(A[(size_t)(ks * 32 + krow) * 64 + nt * 16 + cc]);
    }
    {   // B fragments
        int ct = hi >> 1, ks = hi & 1;
        Bbf[i] = f2bf(B[(size_t)(ks * 32 + krow) * 4096 + ct * 16 + cc]);
    }
}

// k1: 8 bf16 split-K partials of t = x @ A.  Grid (256, 8) x 4 waves.
// Block = 64 rows x ONE ksplit (p = blockIdx.y); wave w owns rows bx*64+w*16.
// All 4 waves stream the SAME 64KB A-slice in lockstep -> L1 serves 3/4 of
// A-frag reads (the R9-R11 mapping gave each wave a different slice: zero
// reuse, 2 MB/CU of L2 traffic — the dominant k1 stream).
// Operand-SWAPPED mfma -> lane holds 4 consecutive t-cols of ONE row ->
// direct 8B stores. No LDS, no barriers.
__global__ __launch_bounds__(256, 8) void k1_xA(
    const float* __restrict__ x, const float* __restrict__ tw,
    const short* __restrict__ Abf, short* __restrict__ t8) {
    const int lane = threadIdx.x & 63;
    const int wave = threadIdx.x >> 6;
    const int rowbase = blockIdx.x * 64 + wave * 16;
    const int rrow = lane & 15;
    const int kgrp = lane >> 4;
    const int p = blockIdx.y;                 // ksplit 0..7 (shared by block)
    const int kbase = p * 512;

    const int row = rowbase + rrow;
    const bool active = (tw[row] != 0.0f);
    const floatx4* xv = (const floatx4*)(x + (size_t)row * 4096 + kbase + kgrp * 8);
    // Abf8[(ksg*4+nt)*64 + lane], ksg = kbase/32 + ks
    const short8* ap = (const short8*)Abf + ((size_t)(kbase >> 5) * 256) + lane;

    floatx4 acc0 = {0,0,0,0}, acc1 = {0,0,0,0}, acc2 = {0,0,0,0}, acc3 = {0,0,0,0};

    // 1-ahead prefetch of the x stream only
    floatx4 cx0 = {0,0,0,0}, cx1 = {0,0,0,0};
    if (active) { cx0 = xv[0]; cx1 = xv[1]; }

    #pragma unroll 4
    for (int ks = 0; ks < 16; ++ks) {
        const int kn = (ks + 1 < 16) ? ks + 1 : 15;
        floatx4 nx0 = {0,0,0,0}, nx1 = {0,0,0,0};
        if (active) { nx0 = xv[kn * 8]; nx1 = xv[kn * 8 + 1]; }

        short8 b0 = ap[ks * 256 + 0 * 64];
        short8 b1 = ap[ks * 256 + 1 * 64];
        short8 b2 = ap[ks * 256 + 2 * 64];
        short8 b3 = ap[ks * 256 + 3 * 64];

        short8 xa;
        xa[0] = f2bf(cx0[0]); xa[1] = f2bf(cx0[1]);
        xa[2] = f2bf(cx0[2]); xa[3] = f2bf(cx0[3]);
        xa[4] = f2bf(cx1[0]); xa[5] = f2bf(cx1[1]);
        xa[6] = f2bf(cx1[2]); xa[7] = f2bf(cx1[3]);

        // swapped: A-matrix fragment as A-operand, x fragment as B-operand.
        // D[m][n] = sum_k A[kbase+k][nt*16+m] * x[rowbase+n][kbase+k]
        acc0 = __builtin_amdgcn_mfma_f32_16x16x32_bf16(b0, xa, acc0, 0, 0, 0);
        acc1 = __builtin_amdgcn_mfma_f32_16x16x32_bf16(b1, xa, acc1, 0, 0, 0);
        acc2 = __builtin_amdgcn_mfma_f32_16x16x32_bf16(b2, xa, acc2, 0, 0, 0);
        acc3 = __builtin_amdgcn_mfma_f32_16x16x32_bf16(b3, xa, acc3, 0, 0, 0);

        cx0 = nx0; cx1 = nx1;
    }

    // D layout: n = lane&15 (token row), m = 4*kgrp + b (t-col within n-tile)
    // -> lane holds t_p[row][nt*16 + kgrp*4 + 0..3]: contiguous 8B per nt.
    short* tp = t8 + (size_t)p * (16384 * 64) + (size_t)row * 64 + kgrp * 4;
    floatx4 accs[4] = {acc0, acc1, acc2, acc3};
    #pragma unroll
    for (int nt = 0; nt < 4; ++nt) {
        short4v v;
        v[0] = f2bf(accs[nt][0]); v[1] = f2bf(accs[nt][1]);
        v[2] = f2bf(accs[nt][2]); v[3] = f2bf(accs[nt][3]);
        *(short4v*)(tp + nt * 16) = v;
    }
}

// k1.5: t = sum of 8 bf16 partials (f32 accumulate). 1M elems / 4 per thread.
__global__ __launch_bounds__(256) void k1_sum(
    const short* __restrict__ t8, short* __restrict__ t) {
    const int i = blockIdx.x * 256 + threadIdx.x;   // 0 .. 262143
    const size_t off = (size_t)i * 4;
    float s0 = 0.f, s1 = 0.f, s2 = 0.f, s3 = 0.f;
    #pragma unroll
    for (int p = 0; p < 8; ++p) {
        short4v v = *(const short4v*)(t8 + (size_t)p * (16384 * 64) + off);
        s0 += bf2f(v[0]); s1 += bf2f(v[1]); s2 += bf2f(v[2]); s3 += bf2f(v[3]);
    }
    short4v r;
    r[0] = f2bf(s0); r[1] = f2bf(s1); r[2] = f2bf(s2); r[3] = f2bf(s3);
    *(short4v*)(t + off) = r;
}

// k2: out = (t @ B) * tw * 2, operand-swapped MFMA, LDS-staged epilogue.
// 16384 blocks x 4 waves: block = 16 rows x 256 cols; wave w computes cols
// [64w,64w+64), stages f32 tile in LDS, then row-linear NT float4 stores
// (lanes 0-15 cover 256B contiguous per row).
__global__ __launch_bounds__(256, 4) void k2_tB(
    const short* __restrict__ t, const float* __restrict__ tw,
    const short* __restrict__ Bbf, float* __restrict__ out) {
    __shared__ float tile[16][257];       // +1 float pad (16.4 KB)

    const int lane = threadIdx.x & 63;
    const int wave = threadIdx.x >> 6;
    const int rg = blockIdx.x >> 4;
    const int cs = blockIdx.x & 15;
    const int rowbase = rg * 16;
    const int colblk = cs * 256;
    const int rrow = lane & 15;
    const int kgrp = lane >> 4;
    const int kofs = kgrp * 8;

    // t fragment (MFMA B-operand): lane holds t[rowbase+rrow][kofs+j]
    const short* t0 = t + (size_t)(rowbase + rrow) * 64 + kofs;
    short8 a0 = *(const short8*)t0;
    short8 a1 = *(const short8*)(t0 + 32);

    // B fragments (MFMA A-operand): Bbf8[(ct*2+ks)*64 + lane], ct = col/16
    const short8* bp = (const short8*)Bbf + (size_t)((colblk + wave * 64) >> 4) * 128 + lane;

    const float w = tw[rowbase + rrow] * 2.0f;

    #pragma unroll
    for (int nt = 0; nt < 4; ++nt) {
        short8 b0 = bp[(nt * 2 + 0) * 64];
        short8 b1 = bp[(nt * 2 + 1) * 64];
        floatx4 acc = {0, 0, 0, 0};
        // swapped: lane holds out[rrow][wave*64 + nt*16 + kgrp*4 + 0..3]
        acc = __builtin_amdgcn_mfma_f32_16x16x32_bf16(b0, a0, acc, 0, 0, 0);
        acc = __builtin_amdgcn_mfma_f32_16x16x32_bf16(b1, a1, acc, 0, 0, 0);
        acc[0] *= w; acc[1] *= w; acc[2] *= w; acc[3] *= w;
        *(floatx4*)&tile[rrow][wave * 64 + nt * 16 + kgrp * 4] = acc;
    }
    __syncthreads();

    // row-linear write-out: wave w -> rows 4w..4w+3; lane l -> row 4w+(l>>4),
    // 16B chunk (l&15)*16B within each 64-float column group q.
    const int orow_i = 4 * wave + (lane >> 4);
    float* orow = out + (size_t)(rowbase + orow_i) * 4096 + colblk;
    #pragma unroll
    for (int q = 0; q < 4; ++q) {
        const int c = q * 64 + rrow * 4;
        floatx4 v = *(const floatx4*)&tile[orow_i][c];
        __builtin_nontemporal_store(v, (floatx4*)(orow + c));
    }
}

extern "C" void kernel_launch(void* const* d_in, const int* in_sizes, int n_in,
                              void* d_out, int out_size, void* d_ws, size_t ws_size,
                              hipStream_t stream) {
    const float* x  = (const float*)d_in[0];   // (8,2048,4096)
    const float* tw = (const float*)d_in[1];   // (8,2048)
    const float* A  = (const float*)d_in[2];   // (4096,64)
    const float* B  = (const float*)d_in[3];   // (64,4096)
    float* out = (float*)d_out;                // (8,2048,4096) fp32

    short* Abf = (short*)d_ws;                 // 512 KB
    short* Bbf = Abf + 262144;                 // 512 KB
    short* t8  = Bbf + 262144;                 // 8 x 16384 x 64 bf16 = 16 MB
    short* t   = t8 + (size_t)8 * 16384 * 64;  // 2 MB

    conv_ab<<<1024, 256, 0, stream>>>(A, B, Abf, Bbf);
    k1_xA<<<dim3(256, 8), 256, 0, stream>>>(x, tw, Abf, t8);
    k1_sum<<<1024, 256, 0, stream>>>(t8, t);
    k2_tB<<<16384, 256, 0, stream>>>(t, tw, Bbf, out);
}